// Round 1
// 786.538 us; speedup vs baseline: 1.0381x; 1.0381x over previous
//
#include <hip/hip_runtime.h>
#include <hip/hip_bf16.h>
#include <math.h>

// Problem constants
#define N_ROWS 512      // B*S
#define D_IN   512
#define E_EMB  256
#define H_DIM  512
#define G_DIM  2048
#define V_DIM  32000
#define IN_LD  1280     // Abuf row: [ x(512) | emb(256) | h(512) ]
#define K_STEPS 4
#define OOV_ID 1
#define TBK 64
#define EMB_SPLIT 25
#define EMB_CHUNK 1280  // 25*1280 = 32000
#define SEGSTRIDE 512   // stats row stride (500 used)

typedef __attribute__((ext_vector_type(4))) float f32x4;
typedef __attribute__((ext_vector_type(8))) short bf16x8;

__device__ inline short f2b(float v) {
    __hip_bfloat16 h = __float2bfloat16(v);
    return *reinterpret_cast<short*>(&h);
}

// async global->LDS, 16B per lane; dest = ldsbase + lane*16 (wave-uniform base)
__device__ inline void gload_lds(const short* g, short* l) {
    __builtin_amdgcn_global_load_lds(
        (const __attribute__((address_space(1))) void*)g,
        (__attribute__((address_space(3))) void*)l, 16, 0, 0);
}

// ---------------------------------------------------------------------------
// MFMA GEMM: C(MxN) = A(MxK,bf16 rm) @ B(NxK,bf16 rm)^T [+bias]
// 256 thr = 4 waves 2x2. global_load_lds staging, XOR-swizzled LDS chunks.
// MODE 0: C = acc + bias[n]   MODE 1: atomicAdd(&C, acc)
// STATS 1: additionally emit per-(row, 64-col segment) (max, sumexp) partials.
template<int TBM, int TBN, int MODE, int STATS>
__global__ __launch_bounds__(256) void k_gemm(
    const short* __restrict__ A, int lda,
    const short* __restrict__ B, int ldb,
    const float* __restrict__ bias,
    float* __restrict__ C, size_t ldc, int Kc,
    float2* __restrict__ stats)
{
    constexpr int WMT = TBM / 2, WNT = TBN / 2;
    constexpr int WM = WMT / 16, WN = WNT / 16;
    __shared__ short As[TBM * 64];
    __shared__ short Bs[TBN * 64];
    const int tid = threadIdx.x;
    const int lane = tid & 63, wid = tid >> 6;
    const int wr = wid & 1, wc = wid >> 1;
    const int quad = lane >> 4, l16 = lane & 15;
    const int m0 = blockIdx.y * TBM, n0 = blockIdx.x * TBN;
    const int kbase = blockIdx.z * Kc;
    // staging lane geometry: 8 rows/instr, 8 chunks of 8 bf16 per row, XOR swizzle
    const int lrow = lane >> 3;
    const int lsw  = ((lane & 7) ^ lrow) * 8;

    f32x4 acc[WM][WN];
#pragma unroll
    for (int i = 0; i < WM; ++i)
#pragma unroll
        for (int j = 0; j < WN; ++j)
#pragma unroll
            for (int r = 0; r < 4; ++r) acc[i][j][r] = 0.0f;

    for (int kt = 0; kt < Kc; kt += TBK) {
        const int k0 = kbase + kt;
#pragma unroll
        for (int ch = wid; ch < TBM / 8; ch += 4)
            gload_lds(&A[(size_t)(m0 + ch * 8 + lrow) * lda + k0 + lsw], &As[ch * 512]);
#pragma unroll
        for (int ch = wid; ch < TBN / 8; ch += 4)
            gload_lds(&B[(size_t)(n0 + ch * 8 + lrow) * ldb + k0 + lsw], &Bs[ch * 512]);
        __syncthreads();
#pragma unroll
        for (int ks = 0; ks < 2; ++ks) {
            bf16x8 af[WM], bfv[WN];
#pragma unroll
            for (int i = 0; i < WM; ++i) {
                int rr = wr * WMT + i * 16 + l16;
                af[i] = *(const bf16x8*)&As[rr * 64 + (((ks * 4 + quad) ^ (l16 & 7)) * 8)];
            }
#pragma unroll
            for (int j = 0; j < WN; ++j) {
                int rr = wc * WNT + j * 16 + l16;
                bfv[j] = *(const bf16x8*)&Bs[rr * 64 + (((ks * 4 + quad) ^ (l16 & 7)) * 8)];
            }
#pragma unroll
            for (int i = 0; i < WM; ++i)
#pragma unroll
                for (int j = 0; j < WN; ++j)
                    acc[i][j] = __builtin_amdgcn_mfma_f32_16x16x32_bf16(af[i], bfv[j], acc[i][j], 0, 0, 0);
        }
        __syncthreads();
    }

    // epilogue. C layout: row = quad*4 + reg, col = l16
    if (MODE == 1) {
#pragma unroll
        for (int i = 0; i < WM; ++i)
#pragma unroll
            for (int j = 0; j < WN; ++j) {
                const int n = n0 + wc * WNT + j * 16 + l16;
#pragma unroll
                for (int r = 0; r < 4; ++r) {
                    const int m = m0 + wr * WMT + i * 16 + quad * 4 + r;
                    atomicAdd(&C[(size_t)m * ldc + n], acc[i][j][r]);
                }
            }
    } else {
        float bv[WN];
#pragma unroll
        for (int j = 0; j < WN; ++j) bv[j] = bias[n0 + wc * WNT + j * 16 + l16];
#pragma unroll
        for (int i = 0; i < WM; ++i) {
            if (!STATS) {
#pragma unroll
                for (int j = 0; j < WN; ++j) {
                    const int n = n0 + wc * WNT + j * 16 + l16;
#pragma unroll
                    for (int r = 0; r < 4; ++r) {
                        const int m = m0 + wr * WMT + i * 16 + quad * 4 + r;
                        C[(size_t)m * ldc + n] = acc[i][j][r] + bv[j];
                    }
                }
            } else {
                float rm[4] = {-1e30f, -1e30f, -1e30f, -1e30f};
                float rs[4] = {0.f, 0.f, 0.f, 0.f};
#pragma unroll
                for (int j = 0; j < WN; ++j)
#pragma unroll
                    for (int r = 0; r < 4; ++r)
                        rm[r] = fmaxf(rm[r], acc[i][j][r] + bv[j]);
#pragma unroll
                for (int j = 0; j < WN; ++j) {
                    const int n = n0 + wc * WNT + j * 16 + l16;
#pragma unroll
                    for (int r = 0; r < 4; ++r) {
                        const int m = m0 + wr * WMT + i * 16 + quad * 4 + r;
                        float z = acc[i][j][r] + bv[j];
                        rs[r] += __expf(z - rm[r]);
                        C[(size_t)m * ldc + n] = z;
                    }
                }
                // merge (max,sum) across the 16 l16-lanes of this quad
#pragma unroll
                for (int mask = 1; mask < 16; mask <<= 1) {
#pragma unroll
                    for (int r = 0; r < 4; ++r) {
                        float om = __shfl_xor(rm[r], mask);
                        float os = __shfl_xor(rs[r], mask);
                        float nm = fmaxf(rm[r], om);
                        rs[r] = rs[r] * __expf(rm[r] - nm) + os * __expf(om - nm);
                        rm[r] = nm;
                    }
                }
                if (l16 == 0) {
                    const int seg = blockIdx.x * 2 + wc;
#pragma unroll
                    for (int r = 0; r < 4; ++r) {
                        const int m = m0 + wr * WMT + i * 16 + quad * 4 + r;
                        stats[(size_t)m * SEGSTRIDE + seg] = make_float2(rm[r], rs[r]);
                    }
                }
            }
        }
    }
}

// ---------------------------------------------------------------------------
// per-launch prep: bf16 weight packs + Abuf init + c zero
__global__ __launch_bounds__(256) void k_prep(
    const float* __restrict__ x, const float* __restrict__ emb_table,
    const float* __restrict__ W_ih, const float* __restrict__ W_hh,
    const float* __restrict__ b_ih, const float* __restrict__ b_hh,
    const float* __restrict__ W_out,
    short* __restrict__ Abuf, short* __restrict__ Wg, float* __restrict__ bsum,
    short* __restrict__ Wout16, float* __restrict__ c)
{
    const int idx0 = blockIdx.x * 256 + threadIdx.x;
    const int gs = gridDim.x * 256;
    const float4* W4 = (const float4*)W_out;
    for (int i = idx0; i < V_DIM * H_DIM / 4; i += gs) {
        float4 v = W4[i];
        short4 o;
        o.x = f2b(v.x); o.y = f2b(v.y); o.z = f2b(v.z); o.w = f2b(v.w);
        ((short4*)Wout16)[i] = o;
    }
    for (int i = idx0; i < G_DIM * IN_LD; i += gs) {
        int g = i / IN_LD, k = i - g * IN_LD;
        float v = (k < D_IN + E_EMB) ? W_ih[(size_t)g * (D_IN + E_EMB) + k]
                                     : W_hh[(size_t)g * H_DIM + (k - (D_IN + E_EMB))];
        Wg[i] = f2b(v);
    }
    for (int i = idx0; i < G_DIM; i += gs) bsum[i] = b_ih[i] + b_hh[i];
    for (int i = idx0; i < N_ROWS * IN_LD; i += gs) {
        int n = i / IN_LD, col = i - n * IN_LD;
        float v;
        if (col < D_IN)              v = x[(size_t)n * D_IN + col];
        else if (col < D_IN + E_EMB) v = emb_table[(size_t)OOV_ID * E_EMB + (col - D_IN)];
        else                         v = 0.0f;
        Abuf[i] = f2b(v);
    }
    for (int i = idx0; i < N_ROWS * H_DIM; i += gs) c[i] = 0.0f;
}

// ---------------------------------------------------------------------------
// emb_T[e][v] = bf16(emb_table[v][e])  (256 x 32000)
__global__ __launch_bounds__(256) void k_trans(const float* __restrict__ emb,
                                               short* __restrict__ embT)
{
    __shared__ float tile[64][65];
    const int v0 = blockIdx.x * 64, e0 = blockIdx.y * 64;
    const int tid = threadIdx.x;
#pragma unroll
    for (int i = 0; i < 16; ++i) {
        int idx = tid + i * 256;
        int vr = idx >> 6, ec = idx & 63;
        tile[vr][ec] = emb[(size_t)(v0 + vr) * E_EMB + e0 + ec];
    }
    __syncthreads();
#pragma unroll
    for (int i = 0; i < 16; ++i) {
        int idx = tid + i * 256;
        int er = idx >> 6, vc = idx & 63;
        embT[(size_t)(e0 + er) * V_DIM + v0 + vc] = f2b(tile[vc][er]);
    }
}

// ---------------------------------------------------------------------------
// LSTM cell (torch order i,f,g,o): c fp32, h -> bf16 into Abuf[:,768:1280)
__global__ __launch_bounds__(256) void k_lstm(const float* __restrict__ gates,
                                              float* __restrict__ c,
                                              short* __restrict__ Abuf)
{
    int idx = blockIdx.x * blockDim.x + threadIdx.x;
    if (idx >= N_ROWS * H_DIM) return;
    int n = idx / H_DIM, j = idx - n * H_DIM;
    const float* gr = gates + (size_t)n * G_DIM;
    float gi = gr[j], gf = gr[j + H_DIM], gg = gr[j + 2 * H_DIM], go = gr[j + 3 * H_DIM];
    float i_ = 1.0f / (1.0f + expf(-gi));
    float f_ = 1.0f / (1.0f + expf(-gf));
    float g_ = tanhf(gg);
    float o_ = 1.0f / (1.0f + expf(-go));
    float cn = f_ * c[idx] + i_ * g_;
    float hn = o_ * tanhf(cn);
    c[idx] = cn;
    Abuf[(size_t)n * IN_LD + (D_IN + E_EMB) + j] = f2b(hn);
}

// ---------------------------------------------------------------------------
// emb_acc fp32 -> bf16 into Abuf[:,512:768)
__global__ __launch_bounds__(256) void k_cvt_emb(const float* __restrict__ emb_acc,
                                                 short* __restrict__ Abuf)
{
    int idx = blockIdx.x * 256 + threadIdx.x;   // 512*256 total
    int n = idx >> 8, e = idx & 255;
    Abuf[(size_t)n * IN_LD + D_IN + e] = f2b(emb_acc[idx]);
}

// ---------------------------------------------------------------------------
// lse[n] = logsumexp over the GEMM-emitted 500 segment stats. One wave per row.
// Also zeroes emb_acc for the next step's split-K atomics when feeding.
__global__ __launch_bounds__(256) void k_lse(const float2* __restrict__ stats,
                                             float* __restrict__ lse,
                                             float* __restrict__ emb_acc,
                                             int feed)
{
    const int tid = threadIdx.x;
    const int lane = tid & 63, wid = tid >> 6;
    const int n = blockIdx.x * 4 + wid;

    float m = -1e30f, s = 0.0f;
    for (int sg = lane; sg < V_DIM / 64; sg += 64) {      // 500 segs, <=8 iters
        float2 p = stats[(size_t)n * SEGSTRIDE + sg];
        float nm = fmaxf(m, p.x);
        s = s * __expf(m - nm) + p.y * __expf(p.x - nm);
        m = nm;
    }
#pragma unroll
    for (int mask = 32; mask > 0; mask >>= 1) {
        float om = __shfl_xor(m, mask);
        float os = __shfl_xor(s, mask);
        float nm = fmaxf(m, om);
        s = s * __expf(m - nm) + os * __expf(om - nm);
        m = nm;
    }
    if (lane == 0) lse[n] = m + __logf(s);

    if (feed) {
        ((float4*)&emb_acc[(size_t)n * E_EMB])[lane] = make_float4(0.f, 0.f, 0.f, 0.f);
    }
}

// ---------------------------------------------------------------------------
// streaming finish: logp = z - lse[row] in place (+ bf16 probs into `last`).
// grid (8, 512): each thread owns 4 float4 -> 4 independent loads in flight,
// fully coalesced, 4096 blocks for latency hiding.
__global__ __launch_bounds__(256) void k_finish(float* __restrict__ out,
                                                short* __restrict__ last,
                                                const float* __restrict__ lse,
                                                int step, int feed)
{
    const int n = blockIdx.y;
    const float l = lse[n];
    float4* row4 = (float4*)(out + ((size_t)n * K_STEPS + step) * V_DIM);
    short4* prow = (short4*)(last + (size_t)n * V_DIM);
    const int c0 = blockIdx.x * 1024 + threadIdx.x;
#pragma unroll
    for (int i = 0; i < 4; ++i) {
        const int c = c0 + i * 256;
        if (c < V_DIM / 4) {
            float4 xv = row4[c];
            xv.x -= l; xv.y -= l; xv.z -= l; xv.w -= l;
            row4[c] = xv;
            if (feed) {
                short4 p;
                p.x = f2b(__expf(xv.x)); p.y = f2b(__expf(xv.y));
                p.z = f2b(__expf(xv.z)); p.w = f2b(__expf(xv.w));
                prow[c] = p;
            }
        }
    }
}

// ---------------------------------------------------------------------------
extern "C" void kernel_launch(void* const* d_in, const int* in_sizes, int n_in,
                              void* d_out, int out_size, void* d_ws, size_t ws_size,
                              hipStream_t stream) {
    (void)in_sizes; (void)n_in; (void)out_size; (void)ws_size;
    const float* x       = (const float*)d_in[0];
    const float* emb_tab = (const float*)d_in[2];
    const float* W_ih    = (const float*)d_in[3];
    const float* b_ih    = (const float*)d_in[4];
    const float* W_hh    = (const float*)d_in[5];
    const float* b_hh    = (const float*)d_in[6];
    const float* W_out   = (const float*)d_in[7];
    const float* b_out   = (const float*)d_in[8];
    float* out = (float*)d_out;

    // workspace carve (~96 MB, all 16B-aligned)
    char* ws = (char*)d_ws;
    short* Abuf   = (short*)ws;  ws += (size_t)N_ROWS * IN_LD * sizeof(short);
    float* c      = (float*)ws;  ws += (size_t)N_ROWS * H_DIM * sizeof(float);
    float* gates  = (float*)ws;  ws += (size_t)N_ROWS * G_DIM * sizeof(float);
    short* last   = (short*)ws;  ws += (size_t)N_ROWS * V_DIM * sizeof(short);
    short* Wout16 = (short*)ws;  ws += (size_t)V_DIM * H_DIM * sizeof(short);
    short* Wg     = (short*)ws;  ws += (size_t)G_DIM * IN_LD * sizeof(short);
    float* bsum   = (float*)ws;  ws += (size_t)G_DIM * sizeof(float);
    short* embT   = (short*)ws;  ws += (size_t)E_EMB * V_DIM * sizeof(short);
    float* emb_acc= (float*)ws;  ws += (size_t)N_ROWS * E_EMB * sizeof(float);
    float2* stats = (float2*)ws; ws += (size_t)N_ROWS * SEGSTRIDE * sizeof(float2);
    float* lse    = (float*)ws;  ws += (size_t)N_ROWS * sizeof(float);

    k_prep<<<2048, 256, 0, stream>>>(x, emb_tab, W_ih, W_hh, b_ih, b_hh, W_out,
                                     Abuf, Wg, bsum, Wout16, c);
    k_trans<<<dim3(V_DIM / 64, E_EMB / 64), 256, 0, stream>>>(emb_tab, embT);

    for (int t = 0; t < K_STEPS; ++t) {
        if (t > 0) {
            // emb_acc += last(512x32000) @ embT(256x32000)^T, split-K
            k_gemm<128, 128, 1, 0><<<dim3(E_EMB / 128, N_ROWS / 128, EMB_SPLIT), 256, 0, stream>>>(
                last, V_DIM, embT, V_DIM, nullptr, emb_acc, E_EMB, EMB_CHUNK, nullptr);
            k_cvt_emb<<<N_ROWS * E_EMB / 256, 256, 0, stream>>>(emb_acc, Abuf);
        }
        // gates = Abuf(512x1280) @ Wg(2048x1280)^T + bsum
        k_gemm<64, 64, 0, 0><<<dim3(G_DIM / 64, N_ROWS / 64, 1), 256, 0, stream>>>(
            Abuf, IN_LD, Wg, IN_LD, bsum, gates, G_DIM, IN_LD, nullptr);
        k_lstm<<<(N_ROWS * H_DIM + 255) / 256, 256, 0, stream>>>(gates, c, Abuf);
        // logits = h(512x512) @ Wout16(32000x512)^T + b_out -> out[:, t, :] (+ stats)
        k_gemm<128, 128, 0, 1><<<dim3(V_DIM / 128, N_ROWS / 128, 1), 256, 0, stream>>>(
            Abuf + (D_IN + E_EMB), IN_LD, Wout16, H_DIM, b_out,
            out + (size_t)t * V_DIM, (size_t)K_STEPS * V_DIM, H_DIM, stats);
        const int feed = (t < K_STEPS - 1) ? 1 : 0;
        k_lse<<<N_ROWS / 4, 256, 0, stream>>>(stats, lse, emb_acc, feed);
        k_finish<<<dim3(8, N_ROWS), 256, 0, stream>>>(out, last, lse, t, feed);
    }
}

// Round 2
// 768.923 us; speedup vs baseline: 1.0619x; 1.0229x over previous
//
#include <hip/hip_runtime.h>
#include <hip/hip_bf16.h>
#include <math.h>

// Problem constants
#define N_ROWS 512      // B*S
#define D_IN   512
#define E_EMB  256
#define H_DIM  512
#define G_DIM  2048
#define V_DIM  32000
#define IN_LD  1280     // Abuf row: [ x(512) | emb(256) | h(512) ]
#define K_STEPS 4
#define OOV_ID 1
#define TBK 64
#define EMB_SPLIT 25
#define EMB_CHUNK 1280  // 25*1280 = 32000
#define SEGSTRIDE 512   // stats row stride (500 used)

typedef __attribute__((ext_vector_type(4))) float f32x4;
typedef __attribute__((ext_vector_type(8))) short bf16x8;

__device__ inline short f2b(float v) {
    __hip_bfloat16 h = __float2bfloat16(v);
    return *reinterpret_cast<short*>(&h);
}

// async global->LDS, 16B per lane; dest = ldsbase + lane*16 (wave-uniform base)
__device__ inline void gload_lds(const short* g, short* l) {
    __builtin_amdgcn_global_load_lds(
        (const __attribute__((address_space(1))) void*)g,
        (__attribute__((address_space(3))) void*)l, 16, 0, 0);
}

// ---------------------------------------------------------------------------
// MFMA GEMM: C(MxN) = A(MxK,bf16 rm) @ B(NxK,bf16 rm)^T [+bias]
// WR_ x WC_ waves (64*WR_*WC_ threads). global_load_lds staging, XOR-swizzled
// LDS chunks (proven 2-barrier structure; only tile/wave geometry templated).
// MODE 0: C = acc + bias[n]            (+STATS: per-64-col (max,sumexp))
// MODE 1: atomicAdd(&C, acc)
// MODE 2: fused LSTM epilogue (requires WC_==1, WNT==64): the 4 N-fragments
//         of a thread are gates i,f,g,o of one j (Wg rows pre-reordered as
//         row' = (j>>4)*64 + gate*16 + (j&15)). Updates cstate, writes bf16 h
//         into hdst (Abuf h-region).
template<int TBM, int TBN, int WR_, int WC_, int MODE, int STATS>
__global__ __launch_bounds__(WR_ * WC_ * 64) void k_gemm(
    const short* __restrict__ A, int lda,
    const short* __restrict__ B, int ldb,
    const float* __restrict__ bias,
    float* __restrict__ C, size_t ldc, int Kc,
    float2* __restrict__ stats,
    float* __restrict__ cstate, short* __restrict__ hdst)
{
    constexpr int NW = WR_ * WC_;
    constexpr int WMT = TBM / WR_, WNT = TBN / WC_;
    constexpr int WM = WMT / 16, WN = WNT / 16;
    __shared__ short As[TBM * 64];
    __shared__ short Bs[TBN * 64];
    const int tid = threadIdx.x;
    const int lane = tid & 63, wid = tid >> 6;
    const int wr = wid % WR_, wc = wid / WR_;
    const int quad = lane >> 4, l16 = lane & 15;
    const int m0 = blockIdx.y * TBM, n0 = blockIdx.x * TBN;
    const int kbase = blockIdx.z * Kc;
    // staging lane geometry: 8 rows/instr, 8 chunks of 8 bf16 per row, XOR swizzle
    const int lrow = lane >> 3;
    const int lsw  = ((lane & 7) ^ lrow) * 8;

    f32x4 acc[WM][WN];
#pragma unroll
    for (int i = 0; i < WM; ++i)
#pragma unroll
        for (int j = 0; j < WN; ++j)
#pragma unroll
            for (int r = 0; r < 4; ++r) acc[i][j][r] = 0.0f;

    for (int kt = 0; kt < Kc; kt += TBK) {
        const int k0 = kbase + kt;
#pragma unroll
        for (int ch = wid; ch < TBM / 8; ch += NW)
            gload_lds(&A[(size_t)(m0 + ch * 8 + lrow) * lda + k0 + lsw], &As[ch * 512]);
#pragma unroll
        for (int ch = wid; ch < TBN / 8; ch += NW)
            gload_lds(&B[(size_t)(n0 + ch * 8 + lrow) * ldb + k0 + lsw], &Bs[ch * 512]);
        __syncthreads();
#pragma unroll
        for (int ks = 0; ks < 2; ++ks) {
            bf16x8 af[WM], bfv[WN];
#pragma unroll
            for (int i = 0; i < WM; ++i) {
                int rr = wr * WMT + i * 16 + l16;
                af[i] = *(const bf16x8*)&As[rr * 64 + (((ks * 4 + quad) ^ (l16 & 7)) * 8)];
            }
#pragma unroll
            for (int j = 0; j < WN; ++j) {
                int rr = wc * WNT + j * 16 + l16;
                bfv[j] = *(const bf16x8*)&Bs[rr * 64 + (((ks * 4 + quad) ^ (l16 & 7)) * 8)];
            }
#pragma unroll
            for (int i = 0; i < WM; ++i)
#pragma unroll
                for (int j = 0; j < WN; ++j)
                    acc[i][j] = __builtin_amdgcn_mfma_f32_16x16x32_bf16(af[i], bfv[j], acc[i][j], 0, 0, 0);
        }
        __syncthreads();
    }

    // epilogue. C frag layout: row = quad*4 + reg, col = l16
    if constexpr (MODE == 1) {
#pragma unroll
        for (int i = 0; i < WM; ++i)
#pragma unroll
            for (int j = 0; j < WN; ++j) {
                const int n = n0 + wc * WNT + j * 16 + l16;
#pragma unroll
                for (int r = 0; r < 4; ++r) {
                    const int m = m0 + wr * WMT + i * 16 + quad * 4 + r;
                    atomicAdd(&C[(size_t)m * ldc + n], acc[i][j][r]);
                }
            }
    } else if constexpr (MODE == 2) {
        // fused LSTM cell: fragments j=0..3 are gates i,f,g,o of column jj
        float bv[WN];
#pragma unroll
        for (int j = 0; j < WN; ++j) bv[j] = bias[n0 + j * 16 + l16];
        const int jj = (n0 >> 2) + l16;   // n0 = bx*64 -> j base = bx*16
#pragma unroll
        for (int i = 0; i < WM; ++i) {
#pragma unroll
            for (int r = 0; r < 4; ++r) {
                const int m = m0 + wr * WMT + i * 16 + quad * 4 + r;
                float gi = acc[i][0][r] + bv[0];
                float gf = acc[i][1][r] + bv[1];
                float gg = acc[i][2][r] + bv[2];
                float go = acc[i][3][r] + bv[3];
                float i_ = 1.0f / (1.0f + expf(-gi));
                float f_ = 1.0f / (1.0f + expf(-gf));
                float g_ = tanhf(gg);
                float o_ = 1.0f / (1.0f + expf(-go));
                const size_t ci = (size_t)m * H_DIM + jj;
                float cn = f_ * cstate[ci] + i_ * g_;
                cstate[ci] = cn;
                hdst[(size_t)m * IN_LD + (D_IN + E_EMB) + jj] = f2b(o_ * tanhf(cn));
            }
        }
    } else {
        float bv[WN];
#pragma unroll
        for (int j = 0; j < WN; ++j) bv[j] = bias[n0 + wc * WNT + j * 16 + l16];
#pragma unroll
        for (int i = 0; i < WM; ++i) {
            if constexpr (!STATS) {
#pragma unroll
                for (int j = 0; j < WN; ++j) {
                    const int n = n0 + wc * WNT + j * 16 + l16;
#pragma unroll
                    for (int r = 0; r < 4; ++r) {
                        const int m = m0 + wr * WMT + i * 16 + quad * 4 + r;
                        C[(size_t)m * ldc + n] = acc[i][j][r] + bv[j];
                    }
                }
            } else {
                float rm[4] = {-1e30f, -1e30f, -1e30f, -1e30f};
                float rs[4] = {0.f, 0.f, 0.f, 0.f};
#pragma unroll
                for (int j = 0; j < WN; ++j)
#pragma unroll
                    for (int r = 0; r < 4; ++r)
                        rm[r] = fmaxf(rm[r], acc[i][j][r] + bv[j]);
#pragma unroll
                for (int j = 0; j < WN; ++j) {
                    const int n = n0 + wc * WNT + j * 16 + l16;
#pragma unroll
                    for (int r = 0; r < 4; ++r) {
                        const int m = m0 + wr * WMT + i * 16 + quad * 4 + r;
                        float z = acc[i][j][r] + bv[j];
                        rs[r] += __expf(z - rm[r]);
                        C[(size_t)m * ldc + n] = z;
                    }
                }
                // merge (max,sum) across the 16 l16-lanes of this quad
#pragma unroll
                for (int mask = 1; mask < 16; mask <<= 1) {
#pragma unroll
                    for (int r = 0; r < 4; ++r) {
                        float om = __shfl_xor(rm[r], mask);
                        float os = __shfl_xor(rs[r], mask);
                        float nm = fmaxf(rm[r], om);
                        rs[r] = rs[r] * __expf(rm[r] - nm) + os * __expf(om - nm);
                        rm[r] = nm;
                    }
                }
                if (l16 == 0) {
                    const int seg = (n0 + wc * WNT) >> 6;
#pragma unroll
                    for (int r = 0; r < 4; ++r) {
                        const int m = m0 + wr * WMT + i * 16 + quad * 4 + r;
                        stats[(size_t)m * SEGSTRIDE + seg] = make_float2(rm[r], rs[r]);
                    }
                }
            }
        }
    }
}

// ---------------------------------------------------------------------------
// per-launch prep: bf16 weight packs + Abuf init + c zero.
// Wg/bsum are REORDERED for the fused-LSTM gates GEMM:
//   row' = (j>>4)*64 + gate*16 + (j&15), orig row g = gate*512 + j
__global__ __launch_bounds__(256) void k_prep(
    const float* __restrict__ x, const float* __restrict__ emb_table,
    const float* __restrict__ W_ih, const float* __restrict__ W_hh,
    const float* __restrict__ b_ih, const float* __restrict__ b_hh,
    const float* __restrict__ W_out,
    short* __restrict__ Abuf, short* __restrict__ Wg, float* __restrict__ bsum,
    short* __restrict__ Wout16, float* __restrict__ c)
{
    const int idx0 = blockIdx.x * 256 + threadIdx.x;
    const int gs = gridDim.x * 256;
    const float4* W4 = (const float4*)W_out;
    for (int i = idx0; i < V_DIM * H_DIM / 4; i += gs) {
        float4 v = W4[i];
        short4 o;
        o.x = f2b(v.x); o.y = f2b(v.y); o.z = f2b(v.z); o.w = f2b(v.w);
        ((short4*)Wout16)[i] = o;
    }
    for (int i = idx0; i < G_DIM * IN_LD; i += gs) {
        int rp = i / IN_LD, k = i - rp * IN_LD;
        int j = ((rp >> 6) << 4) | (rp & 15);
        int gate = (rp >> 4) & 3;
        int g = gate * H_DIM + j;
        float v = (k < D_IN + E_EMB) ? W_ih[(size_t)g * (D_IN + E_EMB) + k]
                                     : W_hh[(size_t)g * H_DIM + (k - (D_IN + E_EMB))];
        Wg[i] = f2b(v);
    }
    for (int i = idx0; i < G_DIM; i += gs) {
        int j = ((i >> 6) << 4) | (i & 15);
        int gate = (i >> 4) & 3;
        int g = gate * H_DIM + j;
        bsum[i] = b_ih[g] + b_hh[g];
    }
    for (int i = idx0; i < N_ROWS * IN_LD; i += gs) {
        int n = i / IN_LD, col = i - n * IN_LD;
        float v;
        if (col < D_IN)              v = x[(size_t)n * D_IN + col];
        else if (col < D_IN + E_EMB) v = emb_table[(size_t)OOV_ID * E_EMB + (col - D_IN)];
        else                         v = 0.0f;
        Abuf[i] = f2b(v);
    }
    for (int i = idx0; i < N_ROWS * H_DIM; i += gs) c[i] = 0.0f;
}

// ---------------------------------------------------------------------------
// emb_T[e][v] = bf16(emb_table[v][e])  (256 x 32000)
__global__ __launch_bounds__(256) void k_trans(const float* __restrict__ emb,
                                               short* __restrict__ embT)
{
    __shared__ float tile[64][65];
    const int v0 = blockIdx.x * 64, e0 = blockIdx.y * 64;
    const int tid = threadIdx.x;
#pragma unroll
    for (int i = 0; i < 16; ++i) {
        int idx = tid + i * 256;
        int vr = idx >> 6, ec = idx & 63;
        tile[vr][ec] = emb[(size_t)(v0 + vr) * E_EMB + e0 + ec];
    }
    __syncthreads();
#pragma unroll
    for (int i = 0; i < 16; ++i) {
        int idx = tid + i * 256;
        int er = idx >> 6, vc = idx & 63;
        embT[(size_t)(e0 + er) * V_DIM + v0 + vc] = f2b(tile[vc][er]);
    }
}

// ---------------------------------------------------------------------------
// emb_acc fp32 -> bf16 into Abuf[:,512:768)
__global__ __launch_bounds__(256) void k_cvt_emb(const float* __restrict__ emb_acc,
                                                 short* __restrict__ Abuf)
{
    int idx = blockIdx.x * 256 + threadIdx.x;   // 512*256 total
    int n = idx >> 8, e = idx & 255;
    Abuf[(size_t)n * IN_LD + D_IN + e] = f2b(emb_acc[idx]);
}

// ---------------------------------------------------------------------------
// lse[n] = logsumexp over the GEMM-emitted 500 segment stats. One wave per row.
// Also zeroes emb_acc for the next step's split-K atomics when feeding.
__global__ __launch_bounds__(256) void k_lse(const float2* __restrict__ stats,
                                             float* __restrict__ lse,
                                             float* __restrict__ emb_acc,
                                             int feed)
{
    const int tid = threadIdx.x;
    const int lane = tid & 63, wid = tid >> 6;
    const int n = blockIdx.x * 4 + wid;

    float m = -1e30f, s = 0.0f;
    for (int sg = lane; sg < V_DIM / 64; sg += 64) {      // 500 segs, <=8 iters
        float2 p = stats[(size_t)n * SEGSTRIDE + sg];
        float nm = fmaxf(m, p.x);
        s = s * __expf(m - nm) + p.y * __expf(p.x - nm);
        m = nm;
    }
#pragma unroll
    for (int mask = 32; mask > 0; mask >>= 1) {
        float om = __shfl_xor(m, mask);
        float os = __shfl_xor(s, mask);
        float nm = fmaxf(m, om);
        s = s * __expf(m - nm) + os * __expf(om - nm);
        m = nm;
    }
    if (lane == 0) lse[n] = m + __logf(s);

    if (feed) {
        ((float4*)&emb_acc[(size_t)n * E_EMB])[lane] = make_float4(0.f, 0.f, 0.f, 0.f);
    }
}

// ---------------------------------------------------------------------------
// streaming finish: logp = z - lse[row] in place (+ bf16 probs into `last`).
__global__ __launch_bounds__(256) void k_finish(float* __restrict__ out,
                                                short* __restrict__ last,
                                                const float* __restrict__ lse,
                                                int step, int feed)
{
    const int n = blockIdx.y;
    const float l = lse[n];
    float4* row4 = (float4*)(out + ((size_t)n * K_STEPS + step) * V_DIM);
    short4* prow = (short4*)(last + (size_t)n * V_DIM);
    const int c0 = blockIdx.x * 1024 + threadIdx.x;
#pragma unroll
    for (int i = 0; i < 4; ++i) {
        const int c = c0 + i * 256;
        if (c < V_DIM / 4) {
            float4 xv = row4[c];
            xv.x -= l; xv.y -= l; xv.z -= l; xv.w -= l;
            row4[c] = xv;
            if (feed) {
                short4 p;
                p.x = f2b(__expf(xv.x)); p.y = f2b(__expf(xv.y));
                p.z = f2b(__expf(xv.z)); p.w = f2b(__expf(xv.w));
                prow[c] = p;
            }
        }
    }
}

// ---------------------------------------------------------------------------
extern "C" void kernel_launch(void* const* d_in, const int* in_sizes, int n_in,
                              void* d_out, int out_size, void* d_ws, size_t ws_size,
                              hipStream_t stream) {
    (void)in_sizes; (void)n_in; (void)out_size; (void)ws_size;
    const float* x       = (const float*)d_in[0];
    const float* emb_tab = (const float*)d_in[2];
    const float* W_ih    = (const float*)d_in[3];
    const float* b_ih    = (const float*)d_in[4];
    const float* W_hh    = (const float*)d_in[5];
    const float* b_hh    = (const float*)d_in[6];
    const float* W_out   = (const float*)d_in[7];
    const float* b_out   = (const float*)d_in[8];
    float* out = (float*)d_out;

    // workspace carve (~96 MB, all 16B-aligned)
    char* ws = (char*)d_ws;
    short* Abuf   = (short*)ws;  ws += (size_t)N_ROWS * IN_LD * sizeof(short);
    float* c      = (float*)ws;  ws += (size_t)N_ROWS * H_DIM * sizeof(float);
    short* last   = (short*)ws;  ws += (size_t)N_ROWS * V_DIM * sizeof(short);
    short* Wout16 = (short*)ws;  ws += (size_t)V_DIM * H_DIM * sizeof(short);
    short* Wg     = (short*)ws;  ws += (size_t)G_DIM * IN_LD * sizeof(short);
    float* bsum   = (float*)ws;  ws += (size_t)G_DIM * sizeof(float);
    short* embT   = (short*)ws;  ws += (size_t)E_EMB * V_DIM * sizeof(short);
    float* emb_acc= (float*)ws;  ws += (size_t)N_ROWS * E_EMB * sizeof(float);
    float2* stats = (float2*)ws; ws += (size_t)N_ROWS * SEGSTRIDE * sizeof(float2);
    float* lse    = (float*)ws;  ws += (size_t)N_ROWS * sizeof(float);

    k_prep<<<2048, 256, 0, stream>>>(x, emb_tab, W_ih, W_hh, b_ih, b_hh, W_out,
                                     Abuf, Wg, bsum, Wout16, c);
    k_trans<<<dim3(V_DIM / 64, E_EMB / 64), 256, 0, stream>>>(emb_tab, embT);

    for (int t = 0; t < K_STEPS; ++t) {
        if (t > 0) {
            // emb_acc += last(512x32000) @ embT(256x32000)^T, split-K, A read once
            k_gemm<128, 256, 2, 4, 1, 0><<<dim3(1, N_ROWS / 128, EMB_SPLIT), 512, 0, stream>>>(
                last, V_DIM, embT, V_DIM, nullptr, emb_acc, E_EMB, EMB_CHUNK,
                nullptr, nullptr, nullptr);
            k_cvt_emb<<<N_ROWS * E_EMB / 256, 256, 0, stream>>>(emb_acc, Abuf);
        }
        // gates GEMM + fused LSTM: Abuf(512x1280) @ Wg'(2048x1280)^T -> c, h
        k_gemm<64, 64, 4, 1, 2, 0><<<dim3(G_DIM / 64, N_ROWS / 64, 1), 256, 0, stream>>>(
            Abuf, IN_LD, Wg, IN_LD, bsum, nullptr, 0, IN_LD, nullptr, c, Abuf);
        // logits = h(512x512) @ Wout16(32000x512)^T + b_out -> out[:, t, :] (+ stats)
        k_gemm<256, 128, 4, 2, 0, 1><<<dim3(V_DIM / 128, N_ROWS / 256, 1), 512, 0, stream>>>(
            Abuf + (D_IN + E_EMB), IN_LD, Wout16, H_DIM, b_out,
            out + (size_t)t * V_DIM, (size_t)K_STEPS * V_DIM, H_DIM, stats,
            nullptr, nullptr);
        const int feed = (t < K_STEPS - 1) ? 1 : 0;
        k_lse<<<N_ROWS / 4, 256, 0, stream>>>(stats, lse, emb_acc, feed);
        k_finish<<<dim3(8, N_ROWS), 256, 0, stream>>>(out, last, lse, t, feed);
    }
}

// Round 3
// 692.824 us; speedup vs baseline: 1.1785x; 1.1098x over previous
//
#include <hip/hip_runtime.h>
#include <hip/hip_bf16.h>
#include <math.h>

// Problem constants
#define N_ROWS 512      // B*S
#define D_IN   512
#define E_EMB  256
#define H_DIM  512
#define G_DIM  2048
#define V_DIM  32000
#define IN_LD  1280     // Abuf row: [ x(512) | emb(256) | h(512) ]
#define K_STEPS 4
#define OOV_ID 1
#define TBK 64
#define EMB_SPLIT 50
#define EMB_CHUNK 640   // 50*640 = 32000
#define SEGSTRIDE 512   // stats row stride (500 used)

typedef __attribute__((ext_vector_type(4))) float f32x4;
typedef __attribute__((ext_vector_type(8))) short bf16x8;
typedef __attribute__((ext_vector_type(8))) _Float16 f16x8;

__device__ inline short f2b(float v) {
    __hip_bfloat16 h = __float2bfloat16(v);
    return *reinterpret_cast<short*>(&h);
}

// async global->LDS, 16B per lane; dest = ldsbase + lane*16 (wave-uniform base)
__device__ inline void gload_lds(const short* g, short* l) {
    __builtin_amdgcn_global_load_lds(
        (const __attribute__((address_space(1))) void*)g,
        (__attribute__((address_space(3))) void*)l, 16, 0, 0);
}

// ---------------------------------------------------------------------------
// MFMA GEMM: C(MxN) = A(MxK,bf16 rm) @ B(NxK,bf16 rm)^T [+bias]
// WR_ x WC_ waves (64*WR_*WC_ threads). global_load_lds staging, XOR-swizzled
// LDS chunks (proven 2-barrier structure; only tile/wave geometry templated).
// MODE 0: C = acc + bias[n]
// MODE 2: fused LSTM epilogue (requires WC_==1, WNT==64): the 4 N-fragments
//         of a thread are gates i,f,g,o of one j (Wg rows pre-reordered as
//         row' = (j>>4)*64 + gate*16 + (j&15)). Updates cstate, writes bf16 h
//         into hdst (Abuf h-region).
// MODE 3: split-K partial store: C[(bz*N_ROWS + m)*ldc + n] = acc  (no atomics)
// MODE 4: z = acc + bias stored as fp16 into C, plus per-64-col (max,sumexp)
//         stats partials (requires WNT==64).
template<int TBM, int TBN, int WR_, int WC_, int MODE>
__global__ __launch_bounds__(WR_ * WC_ * 64) void k_gemm(
    const short* __restrict__ A, int lda,
    const short* __restrict__ B, int ldb,
    const float* __restrict__ bias,
    float* __restrict__ C, size_t ldc, int Kc,
    float2* __restrict__ stats,
    float* __restrict__ cstate, short* __restrict__ hdst)
{
    constexpr int NW = WR_ * WC_;
    constexpr int WMT = TBM / WR_, WNT = TBN / WC_;
    constexpr int WM = WMT / 16, WN = WNT / 16;
    __shared__ short As[TBM * 64];
    __shared__ short Bs[TBN * 64];
    const int tid = threadIdx.x;
    const int lane = tid & 63, wid = tid >> 6;
    const int wr = wid % WR_, wc = wid / WR_;
    const int quad = lane >> 4, l16 = lane & 15;
    const int m0 = blockIdx.y * TBM, n0 = blockIdx.x * TBN;
    const int kbase = blockIdx.z * Kc;
    // staging lane geometry: 8 rows/instr, 8 chunks of 8 bf16 per row, XOR swizzle
    const int lrow = lane >> 3;
    const int lsw  = ((lane & 7) ^ lrow) * 8;

    f32x4 acc[WM][WN];
#pragma unroll
    for (int i = 0; i < WM; ++i)
#pragma unroll
        for (int j = 0; j < WN; ++j)
#pragma unroll
            for (int r = 0; r < 4; ++r) acc[i][j][r] = 0.0f;

    for (int kt = 0; kt < Kc; kt += TBK) {
        const int k0 = kbase + kt;
#pragma unroll
        for (int ch = wid; ch < TBM / 8; ch += NW)
            gload_lds(&A[(size_t)(m0 + ch * 8 + lrow) * lda + k0 + lsw], &As[ch * 512]);
#pragma unroll
        for (int ch = wid; ch < TBN / 8; ch += NW)
            gload_lds(&B[(size_t)(n0 + ch * 8 + lrow) * ldb + k0 + lsw], &Bs[ch * 512]);
        __syncthreads();
#pragma unroll
        for (int ks = 0; ks < 2; ++ks) {
            bf16x8 af[WM], bfv[WN];
#pragma unroll
            for (int i = 0; i < WM; ++i) {
                int rr = wr * WMT + i * 16 + l16;
                af[i] = *(const bf16x8*)&As[rr * 64 + (((ks * 4 + quad) ^ (l16 & 7)) * 8)];
            }
#pragma unroll
            for (int j = 0; j < WN; ++j) {
                int rr = wc * WNT + j * 16 + l16;
                bfv[j] = *(const bf16x8*)&Bs[rr * 64 + (((ks * 4 + quad) ^ (l16 & 7)) * 8)];
            }
#pragma unroll
            for (int i = 0; i < WM; ++i)
#pragma unroll
                for (int j = 0; j < WN; ++j)
                    acc[i][j] = __builtin_amdgcn_mfma_f32_16x16x32_bf16(af[i], bfv[j], acc[i][j], 0, 0, 0);
        }
        __syncthreads();
    }

    // epilogue. C frag layout: row = quad*4 + reg, col = l16
    if constexpr (MODE == 3) {
        float* Cp = C + (size_t)blockIdx.z * N_ROWS * ldc;
#pragma unroll
        for (int i = 0; i < WM; ++i)
#pragma unroll
            for (int j = 0; j < WN; ++j) {
                const int n = n0 + wc * WNT + j * 16 + l16;
#pragma unroll
                for (int r = 0; r < 4; ++r) {
                    const int m = m0 + wr * WMT + i * 16 + quad * 4 + r;
                    Cp[(size_t)m * ldc + n] = acc[i][j][r];
                }
            }
    } else if constexpr (MODE == 2) {
        // fused LSTM cell: fragments j=0..3 are gates i,f,g,o of column jj
        float bv[WN];
#pragma unroll
        for (int j = 0; j < WN; ++j) bv[j] = bias[n0 + j * 16 + l16];
        const int jj = (n0 >> 2) + l16;   // n0 = bx*64 -> j base = bx*16
#pragma unroll
        for (int i = 0; i < WM; ++i) {
#pragma unroll
            for (int r = 0; r < 4; ++r) {
                const int m = m0 + wr * WMT + i * 16 + quad * 4 + r;
                float gi = acc[i][0][r] + bv[0];
                float gf = acc[i][1][r] + bv[1];
                float gg = acc[i][2][r] + bv[2];
                float go = acc[i][3][r] + bv[3];
                float i_ = 1.0f / (1.0f + expf(-gi));
                float f_ = 1.0f / (1.0f + expf(-gf));
                float g_ = tanhf(gg);
                float o_ = 1.0f / (1.0f + expf(-go));
                const size_t ci = (size_t)m * H_DIM + jj;
                float cn = f_ * cstate[ci] + i_ * g_;
                cstate[ci] = cn;
                hdst[(size_t)m * IN_LD + (D_IN + E_EMB) + jj] = f2b(o_ * tanhf(cn));
            }
        }
    } else if constexpr (MODE == 4) {
        _Float16* Ch = (_Float16*)C;
        float bv[WN];
#pragma unroll
        for (int j = 0; j < WN; ++j) bv[j] = bias[n0 + wc * WNT + j * 16 + l16];
#pragma unroll
        for (int i = 0; i < WM; ++i) {
            float rm[4] = {-1e30f, -1e30f, -1e30f, -1e30f};
            float rs[4] = {0.f, 0.f, 0.f, 0.f};
#pragma unroll
            for (int j = 0; j < WN; ++j)
#pragma unroll
                for (int r = 0; r < 4; ++r)
                    rm[r] = fmaxf(rm[r], acc[i][j][r] + bv[j]);
#pragma unroll
            for (int j = 0; j < WN; ++j) {
                const int n = n0 + wc * WNT + j * 16 + l16;
#pragma unroll
                for (int r = 0; r < 4; ++r) {
                    const int m = m0 + wr * WMT + i * 16 + quad * 4 + r;
                    float z = acc[i][j][r] + bv[j];
                    rs[r] += __expf(z - rm[r]);
                    Ch[(size_t)m * ldc + n] = (_Float16)z;
                }
            }
            // merge (max,sum) across the 16 l16-lanes of this quad
#pragma unroll
            for (int mask = 1; mask < 16; mask <<= 1) {
#pragma unroll
                for (int r = 0; r < 4; ++r) {
                    float om = __shfl_xor(rm[r], mask);
                    float os = __shfl_xor(rs[r], mask);
                    float nm = fmaxf(rm[r], om);
                    rs[r] = rs[r] * __expf(rm[r] - nm) + os * __expf(om - nm);
                    rm[r] = nm;
                }
            }
            if (l16 == 0) {
                const int seg = (n0 + wc * WNT) >> 6;
#pragma unroll
                for (int r = 0; r < 4; ++r) {
                    const int m = m0 + wr * WMT + i * 16 + quad * 4 + r;
                    stats[(size_t)m * SEGSTRIDE + seg] = make_float2(rm[r], rs[r]);
                }
            }
        }
    } else {
        float bv[WN];
#pragma unroll
        for (int j = 0; j < WN; ++j) bv[j] = bias[n0 + wc * WNT + j * 16 + l16];
#pragma unroll
        for (int i = 0; i < WM; ++i)
#pragma unroll
            for (int j = 0; j < WN; ++j) {
                const int n = n0 + wc * WNT + j * 16 + l16;
#pragma unroll
                for (int r = 0; r < 4; ++r) {
                    const int m = m0 + wr * WMT + i * 16 + quad * 4 + r;
                    C[(size_t)m * ldc + n] = acc[i][j][r] + bv[j];
                }
            }
    }
}

// ---------------------------------------------------------------------------
// per-launch prep: bf16 weight packs + Abuf init + c zero.
// Wg/bsum are REORDERED for the fused-LSTM gates GEMM:
//   row' = (j>>4)*64 + gate*16 + (j&15), orig row g = gate*512 + j
__global__ __launch_bounds__(256) void k_prep(
    const float* __restrict__ x, const float* __restrict__ emb_table,
    const float* __restrict__ W_ih, const float* __restrict__ W_hh,
    const float* __restrict__ b_ih, const float* __restrict__ b_hh,
    const float* __restrict__ W_out,
    short* __restrict__ Abuf, short* __restrict__ Wg, float* __restrict__ bsum,
    short* __restrict__ Wout16, float* __restrict__ c)
{
    const int idx0 = blockIdx.x * 256 + threadIdx.x;
    const int gs = gridDim.x * 256;
    const float4* W4 = (const float4*)W_out;
    for (int i = idx0; i < V_DIM * H_DIM / 4; i += gs) {
        float4 v = W4[i];
        short4 o;
        o.x = f2b(v.x); o.y = f2b(v.y); o.z = f2b(v.z); o.w = f2b(v.w);
        ((short4*)Wout16)[i] = o;
    }
    for (int i = idx0; i < G_DIM * IN_LD; i += gs) {
        int rp = i / IN_LD, k = i - rp * IN_LD;
        int j = ((rp >> 6) << 4) | (rp & 15);
        int gate = (rp >> 4) & 3;
        int g = gate * H_DIM + j;
        float v = (k < D_IN + E_EMB) ? W_ih[(size_t)g * (D_IN + E_EMB) + k]
                                     : W_hh[(size_t)g * H_DIM + (k - (D_IN + E_EMB))];
        Wg[i] = f2b(v);
    }
    for (int i = idx0; i < G_DIM; i += gs) {
        int j = ((i >> 6) << 4) | (i & 15);
        int gate = (i >> 4) & 3;
        int g = gate * H_DIM + j;
        bsum[i] = b_ih[g] + b_hh[g];
    }
    for (int i = idx0; i < N_ROWS * IN_LD; i += gs) {
        int n = i / IN_LD, col = i - n * IN_LD;
        float v;
        if (col < D_IN)              v = x[(size_t)n * D_IN + col];
        else if (col < D_IN + E_EMB) v = emb_table[(size_t)OOV_ID * E_EMB + (col - D_IN)];
        else                         v = 0.0f;
        Abuf[i] = f2b(v);
    }
    for (int i = idx0; i < N_ROWS * H_DIM; i += gs) c[i] = 0.0f;
}

// ---------------------------------------------------------------------------
// emb_T[e][v] = bf16(emb_table[v][e])  (256 x 32000)
__global__ __launch_bounds__(256) void k_trans(const float* __restrict__ emb,
                                               short* __restrict__ embT)
{
    __shared__ float tile[64][65];
    const int v0 = blockIdx.x * 64, e0 = blockIdx.y * 64;
    const int tid = threadIdx.x;
#pragma unroll
    for (int i = 0; i < 16; ++i) {
        int idx = tid + i * 256;
        int vr = idx >> 6, ec = idx & 63;
        tile[vr][ec] = emb[(size_t)(v0 + vr) * E_EMB + e0 + ec];
    }
    __syncthreads();
#pragma unroll
    for (int i = 0; i < 16; ++i) {
        int idx = tid + i * 256;
        int er = idx >> 6, vc = idx & 63;
        embT[(size_t)(e0 + er) * V_DIM + v0 + vc] = f2b(tile[vc][er]);
    }
}

// ---------------------------------------------------------------------------
// reduce split-K emb partials -> bf16 into Abuf[:,512:768)
__global__ __launch_bounds__(256) void k_embred(const float* __restrict__ ep,
                                                short* __restrict__ Abuf)
{
    int idx = blockIdx.x * 256 + threadIdx.x;   // 512*256 total
    int n = idx >> 8, e = idx & 255;
    float s0 = 0.f, s1 = 0.f;
#pragma unroll
    for (int z = 0; z < EMB_SPLIT; z += 2) {
        s0 += ep[((size_t)z * N_ROWS + n) * E_EMB + e];
        s1 += ep[((size_t)(z + 1) * N_ROWS + n) * E_EMB + e];
    }
    Abuf[(size_t)n * IN_LD + D_IN + e] = f2b(s0 + s1);
}

// ---------------------------------------------------------------------------
// lse[n] = logsumexp over the GEMM-emitted 500 segment stats. One wave per row.
__global__ __launch_bounds__(256) void k_lse(const float2* __restrict__ stats,
                                             float* __restrict__ lse)
{
    const int tid = threadIdx.x;
    const int lane = tid & 63, wid = tid >> 6;
    const int n = blockIdx.x * 4 + wid;

    float m = -1e30f, s = 0.0f;
    for (int sg = lane; sg < V_DIM / 64; sg += 64) {      // 500 segs, <=8 iters
        float2 p = stats[(size_t)n * SEGSTRIDE + sg];
        float nm = fmaxf(m, p.x);
        s = s * __expf(m - nm) + p.y * __expf(p.x - nm);
        m = nm;
    }
#pragma unroll
    for (int mask = 32; mask > 0; mask >>= 1) {
        float om = __shfl_xor(m, mask);
        float os = __shfl_xor(s, mask);
        float nm = fmaxf(m, om);
        s = s * __expf(m - nm) + os * __expf(om - nm);
        m = nm;
    }
    if (lane == 0) lse[n] = m + __logf(s);
}

// ---------------------------------------------------------------------------
// streaming finish: out = fp16 z - lse[row] (fp32), + bf16 probs into `last`.
// grid (8, 512): each block covers 500 chunks of 8 cols.
__global__ __launch_bounds__(256) void k_finish(const _Float16* __restrict__ zbuf,
                                                float* __restrict__ out,
                                                short* __restrict__ last,
                                                const float* __restrict__ lse,
                                                int step, int feed)
{
    const int n = blockIdx.y;
    const float l = lse[n];
    const f16x8* zr = (const f16x8*)(zbuf + (size_t)n * V_DIM);
    float4* row4 = (float4*)(out + ((size_t)n * K_STEPS + step) * V_DIM);
    bf16x8* prow = (bf16x8*)(last + (size_t)n * V_DIM);
#pragma unroll
    for (int it = 0; it < 2; ++it) {
        const int slot = threadIdx.x + it * 256;
        if (slot < 500) {
            const int cidx = blockIdx.x * 500 + slot;
            f16x8 zv = zr[cidx];
            float lp[8];
#pragma unroll
            for (int k = 0; k < 8; ++k) lp[k] = (float)zv[k] - l;
            row4[cidx * 2]     = make_float4(lp[0], lp[1], lp[2], lp[3]);
            row4[cidx * 2 + 1] = make_float4(lp[4], lp[5], lp[6], lp[7]);
            if (feed) {
                bf16x8 p;
#pragma unroll
                for (int k = 0; k < 8; ++k) p[k] = f2b(__expf(lp[k]));
                prow[cidx] = p;
            }
        }
    }
}

// ---------------------------------------------------------------------------
extern "C" void kernel_launch(void* const* d_in, const int* in_sizes, int n_in,
                              void* d_out, int out_size, void* d_ws, size_t ws_size,
                              hipStream_t stream) {
    (void)in_sizes; (void)n_in; (void)out_size; (void)ws_size;
    const float* x       = (const float*)d_in[0];
    const float* emb_tab = (const float*)d_in[2];
    const float* W_ih    = (const float*)d_in[3];
    const float* b_ih    = (const float*)d_in[4];
    const float* W_hh    = (const float*)d_in[5];
    const float* b_hh    = (const float*)d_in[6];
    const float* W_out   = (const float*)d_in[7];
    const float* b_out   = (const float*)d_in[8];
    float* out = (float*)d_out;

    // workspace carve (~125 MB; ws is ~1 GB per harness poison fill)
    char* ws = (char*)d_ws;
    short* Abuf   = (short*)ws;  ws += (size_t)N_ROWS * IN_LD * sizeof(short);
    float* c      = (float*)ws;  ws += (size_t)N_ROWS * H_DIM * sizeof(float);
    short* last   = (short*)ws;  ws += (size_t)N_ROWS * V_DIM * sizeof(short);
    short* Wout16 = (short*)ws;  ws += (size_t)V_DIM * H_DIM * sizeof(short);
    short* Wg     = (short*)ws;  ws += (size_t)G_DIM * IN_LD * sizeof(short);
    float* bsum   = (float*)ws;  ws += (size_t)G_DIM * sizeof(float);
    short* embT   = (short*)ws;  ws += (size_t)E_EMB * V_DIM * sizeof(short);
    float2* stats = (float2*)ws; ws += (size_t)N_ROWS * SEGSTRIDE * sizeof(float2);
    float* lse    = (float*)ws;  ws += (size_t)N_ROWS * sizeof(float);
    ws = (char*)(((size_t)ws + 255) & ~(size_t)255);
    // scratch union: zbuf (32.77 MB) / emb partials (26.2 MB) — disjoint lifetimes
    _Float16* zbuf = (_Float16*)ws;
    float* epart   = (float*)ws;
    ws += (size_t)N_ROWS * V_DIM * sizeof(_Float16);

    k_prep<<<2048, 256, 0, stream>>>(x, emb_tab, W_ih, W_hh, b_ih, b_hh, W_out,
                                     Abuf, Wg, bsum, Wout16, c);
    k_trans<<<dim3(V_DIM / 64, E_EMB / 64), 256, 0, stream>>>(emb_tab, embT);

    for (int t = 0; t < K_STEPS; ++t) {
        if (t > 0) {
            // epart[z] = last(512x32000) @ embT(256x32000)^T chunk, no atomics
            k_gemm<128, 256, 2, 4, 3><<<dim3(1, N_ROWS / 128, EMB_SPLIT), 512, 0, stream>>>(
                last, V_DIM, embT, V_DIM, nullptr, epart, E_EMB, EMB_CHUNK,
                nullptr, nullptr, nullptr);
            k_embred<<<N_ROWS * E_EMB / 256, 256, 0, stream>>>(epart, Abuf);
        }
        // gates GEMM + fused LSTM: Abuf(512x1280) @ Wg'(2048x1280)^T -> c, h
        k_gemm<64, 64, 4, 1, 2><<<dim3(G_DIM / 64, N_ROWS / 64, 1), 256, 0, stream>>>(
            Abuf, IN_LD, Wg, IN_LD, bsum, nullptr, 0, IN_LD, nullptr, c, Abuf);
        // logits: h(512x512) @ Wout16(32000x512)^T + b_out -> zbuf fp16 + stats
        k_gemm<256, 128, 4, 2, 4><<<dim3(V_DIM / 128, N_ROWS / 256, 1), 512, 0, stream>>>(
            Abuf + (D_IN + E_EMB), IN_LD, Wout16, H_DIM, b_out,
            (float*)zbuf, V_DIM, H_DIM, stats, nullptr, nullptr);
        const int feed = (t < K_STEPS - 1) ? 1 : 0;
        k_lse<<<N_ROWS / 4, 256, 0, stream>>>(stats, lse);
        k_finish<<<dim3(8, N_ROWS), 256, 0, stream>>>(zbuf, out, last, lse, t, feed);
    }
}